// Round 8
// baseline (78.269 us; speedup 1.0000x reference)
//
#include <hip/hip_runtime.h>
#include <hip/hip_bf16.h>

#define NH 32          // heads
#define NV 1537        // edge_enc_w rows
#define ND 20          // MULTI_HOP_MAX_DIST
#define NB 16          // batch
#define NN 64          // nodes

#define TROWS (ND*NV)                    // 30740
#define TBLOCKS ((TROWS + 31) / 32)      // 961  (32 rows per block)
#define BORDER_N (NB*NH*65 + NB*NH*64)   // 66048
#define BBLOCKS ((BORDER_N + 255) / 256) // 258

typedef unsigned int   u32;
typedef unsigned short u16;
typedef __attribute__((ext_vector_type(2))) float          f32x2;
typedef __attribute__((ext_vector_type(4))) int            v4i;
typedef __attribute__((ext_vector_type(4))) float          v4f;
typedef __attribute__((ext_vector_type(4))) unsigned short v4h;

// ---- fp8 e4m3 helpers (HW cvt; asm fallback keeps the same semantics) ----
__device__ __forceinline__ f32x2 fp8x2_to_f32(u32 u) {
#if __has_builtin(__builtin_amdgcn_cvt_pk_f32_fp8)
    return __builtin_amdgcn_cvt_pk_f32_fp8(u, false);   // decodes bytes 0,1
#else
    f32x2 r;
    asm("v_cvt_pk_f32_fp8 %0, %1" : "=v"(r) : "v"(u));
    return r;
#endif
}
__device__ __forceinline__ u32 f32x4_to_fp8(float a0, float a1, float a2, float a3) {
#if __has_builtin(__builtin_amdgcn_cvt_pk_fp8_f32)
    u32 u = __builtin_amdgcn_cvt_pk_fp8_f32(a0, a1, 0u, false);
    u     = __builtin_amdgcn_cvt_pk_fp8_f32(a2, a3, u,  true);
    return u;
#else
    u32 lo, hi;
    asm("v_cvt_pk_fp8_f32 %0, %1, %2" : "=v"(lo) : "v"(a0), "v"(a1));
    asm("v_cvt_pk_fp8_f32 %0, %1, %2" : "=v"(hi) : "v"(a2), "v"(a3));
    return (lo & 0xffffu) | (hi << 16);
#endif
}

// ---------------- Kernel 1: build T (fp8 e4m3, x256) + borders, fused ----------------
// T row = 32 heads x 1B = 32B = 8 u32. 8 lanes per row, lane l packs heads 4l..4l+3.
__global__ void __launch_bounds__(256)
prep_kernel(const float* __restrict__ enc,     // (1537,32)
            const float* __restrict__ wdis,    // (20,32,32)
            const float* __restrict__ ab,      // (B,65,65)
            const float* __restrict__ tokw,    // (32,)
            u32* __restrict__ T8,              // (30740, 8) u32 out
            float* __restrict__ out) {         // (B,32,65,65)
    int blk = blockIdx.x;
    if (blk < TBLOCKS) {
        int row = blk * 32 + (threadIdx.x >> 3);
        int l   = threadIdx.x & 7;
        if (row >= TROWS) return;
        int d = row / NV, v = row - d * NV;
        const float* e = enc + v * NH;
        const float* w = wdis + d * NH * NH + 4 * l;
        float a0 = 0.f, a1 = 0.f, a2 = 0.f, a3 = 0.f;
#pragma unroll
        for (int k = 0; k < NH; ++k) {
            float ev = e[k];                       // broadcast within row-group
            float4 w4 = *(const float4*)(w + k * NH);  // 8 lanes x 16B = 128B
            a0 += ev * w4.x; a1 += ev * w4.y;
            a2 += ev * w4.z; a3 += ev * w4.w;
        }
        T8[row * 8 + l] = f32x4_to_fp8(a0 * 256.f, a1 * 256.f,
                                       a2 * 256.f, a3 * 256.f);
    } else {
        int t = (blk - TBLOCKS) * 256 + threadIdx.x;
        const int nA = NB * NH * 65;   // row 0, all j
        if (t < nA) {
            int j = t % 65; int bh = t / 65; int h = bh & 31; int b = bh >> 5;
            __builtin_nontemporal_store(2.0f * ab[b * 4225 + j] + tokw[h],
                &out[((size_t)(b * NH + h) * 65 + 0) * 65 + j]);
        } else {
            t -= nA;                   // col 0, i >= 1
            if (t >= NB * NH * 64) return;
            int i = (t % 64) + 1; int bh = t / 64; int h = bh & 31; int b = bh >> 5;
            __builtin_nontemporal_store(2.0f * ab[b * 4225 + i * 65] + tokw[h],
                &out[((size_t)(b * NH + h) * 65 + i) * 65 + 0]);
        }
    }
}

// ---------------- Kernel 2: interior, half-row blocks (R4 structure) ----------------
// block = (b, i, half): 32 cells x 32 heads, 256 threads, 8 blocks/CU.
// group = 8 lanes = 1 cell; lane l covers heads {4l..4l+3} via one u32 (fp8x4)
// per gather. Indices pre-biased (d*NV+idx) as u16, read 4-at-a-time (ds_read_b64).
__global__ void __launch_bounds__(256, 8)
main_kernel(const float* __restrict__ ab,          // (B,65,65)
            const int*   __restrict__ spos,        // (B,64,64)
            const int*   __restrict__ eidx,        // (B,64,64,20,3)
            const float* __restrict__ mask2d,      // (B,)
            const float* __restrict__ spw,         // (512,32)
            const u32*   __restrict__ Tw,          // T rows as 8x u32 (fp8)
            float*       __restrict__ out) {       // (B,32,65,65)
    __shared__ __align__(8) u16 sidx[32 * 60];     // 3840 B, pre-biased
    __shared__ float comb[32 * 33];                // [h][j] padded, 4224 B

    int tid  = threadIdx.x;
    int blk  = blockIdx.x;              // 0..2047
    int half = blk & 1;
    int bi   = blk >> 1;                // b*64 + i
    int b = bi >> 6, i = bi & 63;
    int j0 = half * 32;

    // stage 32 cells x 60 indices = 480 int4 -> u16 pre-biased (d*NV+idx)
    const v4i* ep4 = (const v4i*)(eidx + (size_t)(bi * 64 + j0) * 60);
    {
        v4i q = __builtin_nontemporal_load(ep4 + tid);
        int p0 = (tid % 15) * 4;
        v4h sv;
        sv.x = (u16)(q.x + ((p0 + 0) / 3) * NV);
        sv.y = (u16)(q.y + ((p0 + 1) / 3) * NV);
        sv.z = (u16)(q.z + ((p0 + 2) / 3) * NV);
        sv.w = (u16)(q.w + ((p0 + 3) / 3) * NV);
        *(v4h*)(sidx + 4 * tid) = sv;
        if (tid < 224) {
            int e = 256 + tid;
            v4i q2 = __builtin_nontemporal_load(ep4 + e);
            int p1 = (e % 15) * 4;
            v4h s2;
            s2.x = (u16)(q2.x + ((p1 + 0) / 3) * NV);
            s2.y = (u16)(q2.y + ((p1 + 1) / 3) * NV);
            s2.z = (u16)(q2.z + ((p1 + 2) / 3) * NV);
            s2.w = (u16)(q2.w + ((p1 + 3) / 3) * NV);
            *(v4h*)(sidx + 4 * e) = s2;
        }
    }
    __syncthreads();

    int g = tid >> 3, l = tid & 7;      // cell jj = g, lane = head-quad
    const u16* mi = sidx + g * 60;
    const u32* Tl = Tw + l;             // lane's u32 column; row stride 8 u32 = 32B

    f32x2 accA = {0.f, 0.f}, accB = {0.f, 0.f};
#pragma unroll
    for (int t = 0; t < 15; ++t) {
        v4h q = *(const v4h*)(mi + 4 * t);          // one ds_read_b64
#pragma unroll
        for (int c = 0; c < 4; ++c) {
            u32 idx = (c == 0) ? q.x : (c == 1) ? q.y : (c == 2) ? q.z : q.w;
            u32 u = __builtin_nontemporal_load(Tl + (idx << 3));
            accA += fp8x2_to_f32(u);        // heads 4l, 4l+1
            accB += fp8x2_to_f32(u >> 16);  // heads 4l+2, 4l+3
        }
    }

    int s  = spos[bi * 64 + j0 + g];
    int sp = (s == 0) ? 1 : s;
    sp = (sp > 1) ? sp - 1 : sp;
    sp = (sp > ND) ? ND : sp;
    float m   = mask2d[b];
    float esc = m / (768.0f * (float)sp);          // /3sp and /256 fp8 scale
    v4f spv = ((const v4f*)(spw + s * NH))[l];     // heads 4l..4l+3, 16B/lane
    comb[(4 * l + 0) * 33 + g] = spv.x * m + accA.x * esc;
    comb[(4 * l + 1) * 33 + g] = spv.y * m + accA.y * esc;
    comb[(4 * l + 2) * 33 + g] = spv.z * m + accB.x * esc;
    comb[(4 * l + 3) * 33 + g] = spv.w * m + accB.y * esc;
    __syncthreads();

    // write phase: 32 consecutive j per 32-lane half-wave -> 128B segments
    int jw = tid & 31, hh = tid >> 5;   // hh in 0..7
    float a2b = 2.0f * ab[(b * 65 + i + 1) * 65 + (j0 + jw + 1)];
#pragma unroll
    for (int p = 0; p < 4; ++p) {
        int h = p * 8 + hh;
        __builtin_nontemporal_store(a2b + comb[h * 33 + jw],
            &out[((size_t)(b * NH + h) * 65 + i + 1) * 65 + (j0 + jw + 1)]);
    }
}

extern "C" void kernel_launch(void* const* d_in, const int* in_sizes, int n_in,
                              void* d_out, int out_size, void* d_ws, size_t ws_size,
                              hipStream_t stream) {
    const float* attn_bias   = (const float*)d_in[0];
    const int*   spatial_pos = (const int*)  d_in[1];
    // d_in[2] = x (unused), d_in[4] = attn_edge_type (unused)
    const int*   edge_input  = (const int*)  d_in[3];
    const float* mask_2d     = (const float*)d_in[5];
    const float* edge_enc_w  = (const float*)d_in[6];
    const float* edge_dis_w  = (const float*)d_in[7];
    const float* spatial_w   = (const float*)d_in[8];
    const float* token_w     = (const float*)d_in[9];
    float* out = (float*)d_out;
    u32* T8 = (u32*)d_ws;   // 30740 * 32B = 983,680 B

    // Kernel 1: build T (fp8) + borders
    prep_kernel<<<TBLOCKS + BBLOCKS, 256, 0, stream>>>(edge_enc_w, edge_dis_w,
                                                       attn_bias, token_w, T8, out);
    // Kernel 2: interior (half-row blocks, 8-lane groups, 8 blocks/CU)
    main_kernel<<<NB * NN * 2, 256, 0, stream>>>(attn_bias, spatial_pos, edge_input,
                                                 mask_2d, spatial_w, T8, out);
}

// Round 9
// 30.337 us; speedup vs baseline: 2.5800x; 2.5800x over previous
//
#include <hip/hip_runtime.h>
#include <hip/hip_bf16.h>

#define NH 32          // heads
#define NV 1537        // edge_enc_w rows
#define ND 20          // MULTI_HOP_MAX_DIST
#define NB 16          // batch
#define NN 64          // nodes

#define TROWS (ND*NV)                    // 30740
#define TBLOCKS ((TROWS + 31) / 32)      // 961  (32 rows per block)
#define BORDER_N (NB*NH*65 + NB*NH*64)   // 66048
#define BBLOCKS ((BORDER_N + 255) / 256) // 258

typedef unsigned int u32;
typedef __attribute__((ext_vector_type(2))) float f32x2;
typedef __attribute__((ext_vector_type(4))) int   v4i;
typedef __attribute__((ext_vector_type(4))) float v4f;

// ---- fp8 e4m3 helpers (HW cvt; asm fallback keeps the same semantics) ----
__device__ __forceinline__ f32x2 fp8x2_to_f32(u32 u) {
#if __has_builtin(__builtin_amdgcn_cvt_pk_f32_fp8)
    return __builtin_amdgcn_cvt_pk_f32_fp8(u, false);   // decodes bytes 0,1
#else
    f32x2 r;
    asm("v_cvt_pk_f32_fp8 %0, %1" : "=v"(r) : "v"(u));
    return r;
#endif
}
__device__ __forceinline__ u32 f32x4_to_fp8(float a0, float a1, float a2, float a3) {
#if __has_builtin(__builtin_amdgcn_cvt_pk_fp8_f32)
    u32 u = __builtin_amdgcn_cvt_pk_fp8_f32(a0, a1, 0u, false);
    u     = __builtin_amdgcn_cvt_pk_fp8_f32(a2, a3, u,  true);
    return u;
#else
    u32 lo, hi;
    asm("v_cvt_pk_fp8_f32 %0, %1, %2" : "=v"(lo) : "v"(a0), "v"(a1));
    asm("v_cvt_pk_fp8_f32 %0, %1, %2" : "=v"(hi) : "v"(a2), "v"(a3));
    return (lo & 0xffffu) | (hi << 16);
#endif
}

// ---------------- Kernel 1: build T (fp8 e4m3, x256) + borders, fused ----------------
// T row = 32 heads x 1B = 32B = 8 u32. 8 lanes per row, lane l packs heads 4l..4l+3.
__global__ void __launch_bounds__(256)
prep_kernel(const float* __restrict__ enc,     // (1537,32)
            const float* __restrict__ wdis,    // (20,32,32)
            const float* __restrict__ ab,      // (B,65,65)
            const float* __restrict__ tokw,    // (32,)
            u32* __restrict__ T8,              // (30740, 8) u32 out
            float* __restrict__ out) {         // (B,32,65,65)
    int blk = blockIdx.x;
    if (blk < TBLOCKS) {
        int row = blk * 32 + (threadIdx.x >> 3);
        int l   = threadIdx.x & 7;
        if (row >= TROWS) return;
        int d = row / NV, v = row - d * NV;
        const float* e = enc + v * NH;
        const float* w = wdis + d * NH * NH + 4 * l;
        float a0 = 0.f, a1 = 0.f, a2 = 0.f, a3 = 0.f;
#pragma unroll
        for (int k = 0; k < NH; ++k) {
            float ev = e[k];                       // broadcast within row-group
            float4 w4 = *(const float4*)(w + k * NH);  // 8 lanes x 16B = 128B
            a0 += ev * w4.x; a1 += ev * w4.y;
            a2 += ev * w4.z; a3 += ev * w4.w;
        }
        T8[row * 8 + l] = f32x4_to_fp8(a0 * 256.f, a1 * 256.f,
                                       a2 * 256.f, a3 * 256.f);
    } else {
        int t = (blk - TBLOCKS) * 256 + threadIdx.x;
        const int nA = NB * NH * 65;   // row 0, all j
        if (t < nA) {
            int j = t % 65; int bh = t / 65; int h = bh & 31; int b = bh >> 5;
            __builtin_nontemporal_store(2.0f * ab[b * 4225 + j] + tokw[h],
                &out[((size_t)(b * NH + h) * 65 + 0) * 65 + j]);
        } else {
            t -= nA;                   // col 0, i >= 1
            if (t >= NB * NH * 64) return;
            int i = (t % 64) + 1; int bh = t / 64; int h = bh & 31; int b = bh >> 5;
            __builtin_nontemporal_store(2.0f * ab[b * 4225 + i * 65] + tokw[h],
                &out[((size_t)(b * NH + h) * 65 + i) * 65 + 0]);
        }
    }
}

// ---------------- Kernel 2: interior, half-row blocks (R7 structure) ----------------
// block = (b, i, half): 32 cells x 32 heads, 256 threads.
// group = 8 lanes = 1 cell; lane l covers heads {4l..4l+3} via one u32 (fp8x4)
// per gather. Inner loop: explicit 3x20 batched pipeline (20 loads in flight)
// to hide ~200cy L2 latency. T loads are NORMAL (cached) - nt was the R8 bug.
__global__ void __launch_bounds__(256, 4)
main_kernel(const float* __restrict__ ab,          // (B,65,65)
            const int*   __restrict__ spos,        // (B,64,64)
            const int*   __restrict__ eidx,        // (B,64,64,20,3)
            const float* __restrict__ mask2d,      // (B,)
            const float* __restrict__ spw,         // (512,32)
            const u32*   __restrict__ Tw,          // T rows as 8x u32 (fp8)
            float*       __restrict__ out) {       // (B,32,65,65)
    __shared__ __align__(16) int sidx[32 * 60];    // 7680 B
    __shared__ float comb[32 * 33];                // [h][j] padded, 4224 B

    int tid  = threadIdx.x;
    int blk  = blockIdx.x;              // 0..2047
    int half = blk & 1;
    int bi   = blk >> 1;                // b*64 + i
    int b = bi >> 6, i = bi & 63;
    int j0 = half * 32;

    // stage 32 cells x 60 indices = 480 int4, nontemporal (streaming input)
    const v4i* ep4 = (const v4i*)(eidx + (size_t)(bi * 64 + j0) * 60);
    v4i* s4 = (v4i*)sidx;
    s4[tid] = __builtin_nontemporal_load(ep4 + tid);
    if (tid < 224) s4[256 + tid] = __builtin_nontemporal_load(ep4 + 256 + tid);
    __syncthreads();

    int g = tid >> 3, l = tid & 7;      // cell jj = g, lane = head-quad
    const int* mi = sidx + g * 60;
    const u32* Tl = Tw + l;             // per-lane u32 column; row stride 8 u32

    f32x2 accA = {0.f, 0.f}, accB = {0.f, 0.f};
#pragma unroll
    for (int t = 0; t < 3; ++t) {       // 3 batches of 20
        u32 off[20];
        u32 val[20];
#pragma unroll
        for (int k = 0; k < 20; ++k) {  // offsets (ds_read + addr math)
            int p = t * 20 + k;         // compile-time
            int d = p / 3;              // compile-time
            off[k] = (u32)(d * NV + mi[p]) * 8u;
        }
#pragma unroll
        for (int k = 0; k < 20; ++k)    // 20 independent loads in flight
            val[k] = Tl[off[k]];
#pragma unroll
        for (int k = 0; k < 20; ++k) {  // decode + accumulate
            accA += fp8x2_to_f32(val[k]);        // heads 4l, 4l+1
            accB += fp8x2_to_f32(val[k] >> 16);  // heads 4l+2, 4l+3
        }
    }

    int s  = spos[bi * 64 + j0 + g];
    int sp = (s == 0) ? 1 : s;
    sp = (sp > 1) ? sp - 1 : sp;
    sp = (sp > ND) ? ND : sp;
    float m   = mask2d[b];
    float esc = m / (768.0f * (float)sp);          // /3sp and /256 fp8 scale
    v4f spv = ((const v4f*)(spw + s * NH))[l];     // heads 4l..4l+3, 16B/lane
    comb[(4 * l + 0) * 33 + g] = spv.x * m + accA.x * esc;
    comb[(4 * l + 1) * 33 + g] = spv.y * m + accA.y * esc;
    comb[(4 * l + 2) * 33 + g] = spv.z * m + accB.x * esc;
    comb[(4 * l + 3) * 33 + g] = spv.w * m + accB.y * esc;
    __syncthreads();

    // write phase: 32 consecutive j per 32-lane half-wave -> 128B segments
    int jw = tid & 31, hh = tid >> 5;   // hh in 0..7
    float a2b = 2.0f * ab[(b * 65 + i + 1) * 65 + (j0 + jw + 1)];
#pragma unroll
    for (int p = 0; p < 4; ++p) {
        int h = p * 8 + hh;
        __builtin_nontemporal_store(a2b + comb[h * 33 + jw],
            &out[((size_t)(b * NH + h) * 65 + i + 1) * 65 + (j0 + jw + 1)]);
    }
}

extern "C" void kernel_launch(void* const* d_in, const int* in_sizes, int n_in,
                              void* d_out, int out_size, void* d_ws, size_t ws_size,
                              hipStream_t stream) {
    const float* attn_bias   = (const float*)d_in[0];
    const int*   spatial_pos = (const int*)  d_in[1];
    // d_in[2] = x (unused), d_in[4] = attn_edge_type (unused)
    const int*   edge_input  = (const int*)  d_in[3];
    const float* mask_2d     = (const float*)d_in[5];
    const float* edge_enc_w  = (const float*)d_in[6];
    const float* edge_dis_w  = (const float*)d_in[7];
    const float* spatial_w   = (const float*)d_in[8];
    const float* token_w     = (const float*)d_in[9];
    float* out = (float*)d_out;
    u32* T8 = (u32*)d_ws;   // 30740 * 32B = 983,680 B

    // Kernel 1: build T (fp8) + borders
    prep_kernel<<<TBLOCKS + BBLOCKS, 256, 0, stream>>>(edge_enc_w, edge_dis_w,
                                                       attn_bias, token_w, T8, out);
    // Kernel 2: interior (half-row blocks, 8-lane groups, batched pipeline)
    main_kernel<<<NB * NN * 2, 256, 0, stream>>>(attn_bias, spatial_pos, edge_input,
                                                 mask_2d, spatial_w, T8, out);
}